// Round 16
// baseline (336.469 us; speedup 1.0000x reference)
//
#include <hip/hip_runtime.h>
#include <cmath>

typedef __attribute__((ext_vector_type(8))) short short8;
typedef __attribute__((ext_vector_type(4))) float f32x4;
typedef __attribute__((ext_vector_type(4))) unsigned short us4;
typedef unsigned short u16;

#define BATCH 8192
static constexpr size_t BH = (size_t)BATCH * 256;
#define LPAD 264  // u16 LDS row stride (528 B)

__device__ __forceinline__ u16 f2bf(float f) {
    union { float f; unsigned u; } v; v.f = f;
    unsigned r = v.u + 0x7FFFu + ((v.u >> 16) & 1u);
    return (u16)(r >> 16);
}
__device__ __forceinline__ float bf2f(u16 u) {
    union { unsigned u; float f; } v; v.u = ((unsigned)u) << 16;
    return v.f;
}
__device__ __forceinline__ float sigmoidf_(float x) {
    return 1.f / (1.f + __expf(-x));
}
__device__ __forceinline__ short8 cvt8(const float* p) {
    f32x4 lo = *(const f32x4*)p, hi = *(const f32x4*)(p + 4);
    short8 t;
    t[0] = (short)f2bf(lo[0]); t[1] = (short)f2bf(lo[1]);
    t[2] = (short)f2bf(lo[2]); t[3] = (short)f2bf(lo[3]);
    t[4] = (short)f2bf(hi[0]); t[5] = (short)f2bf(hi[1]);
    t[6] = (short)f2bf(hi[2]); t[7] = (short)f2bf(hi[3]);
    return t;
}
__device__ __forceinline__ float dot4(const f32x4& a, const float* b) {
    return a[0] * b[0] + a[1] * b[1] + a[2] * b[2] + a[3] * b[3];
}

// ---------------- weight conversion ----------------
// dst layout (u16 units, 65536 per chunk):
//  c0: embed_w | c1..4: wtn[l] | c5..8: wsn[l] | c9..12: wt[l][512:768]
//  c13..16: ws[l][0:256] | c17..20: ws[l][512:768] | c21: out_w
__global__ __launch_bounds__(256) void convert_weights(
    const float* __restrict__ embed_w, const float* __restrict__ wtn,
    const float* __restrict__ wsn, const float* __restrict__ wt,
    const float* __restrict__ ws, const float* __restrict__ out_w,
    u16* __restrict__ dst)
{
    int idx = blockIdx.x * 256 + threadIdx.x;
    int e = idx * 4;
    if (e >= 22 * 65536) return;
    int c = e >> 16, o = e & 65535;
    const float* src;
    if (c == 0)      src = embed_w + o;
    else if (c < 5)  src = wtn + (size_t)(c - 1) * 65536 + o;
    else if (c < 9)  src = wsn + (size_t)(c - 5) * 65536 + o;
    else if (c < 13) src = wt + (size_t)(c - 9) * 768 * 256 + 512 * 256 + o;
    else if (c < 17) src = ws + (size_t)(c - 13) * 768 * 256 + o;
    else if (c < 21) src = ws + (size_t)(c - 17) * 768 * 256 + 512 * 256 + o;
    else             src = out_w + o;
    f32x4 v = *(const f32x4*)src;
    us4 r;
#pragma unroll
    for (int j = 0; j < 4; ++j) r[j] = f2bf(v[j]);
    *(us4*)(dst + e) = r;
}

// ---------------- embed_dual: S0 = x@We^T+b -> (global, LDS); sn/tn for layer 0 ----------------
// grid 512, 256 thr (4 waves), 16 rows/block; wave w -> cols 64w..64w+63.
__global__ __launch_bounds__(256, 4) void embed_dual(
    const float* __restrict__ x, const float* __restrict__ t_att,
    const u16* __restrict__ Wbf,
    const float* __restrict__ embed_b,
    const float* __restrict__ btn, const float* __restrict__ bsn,
    u16* __restrict__ S_hist, u16* __restrict__ sn_g, u16* __restrict__ tn_g)
{
    __shared__ __align__(16) u16 Ax[16][LPAD];
    __shared__ __align__(16) u16 Tn[16][LPAD];
    __shared__ __align__(16) u16 S0[16][LPAD];
    const int t = threadIdx.x;
    const int row0 = blockIdx.x * 16;
    {
        int r = t >> 4, c0 = (t & 15) * 16;
        const float* px = x + (size_t)(row0 + r) * 256 + c0;
        const float* pt = t_att + (size_t)7 * BH + (size_t)(row0 + r) * 256 + c0;
        *(short8*)&Ax[r][c0]     = cvt8(px);
        *(short8*)&Ax[r][c0 + 8] = cvt8(px + 8);
        *(short8*)&Tn[r][c0]     = cvt8(pt);
        *(short8*)&Tn[r][c0 + 8] = cvt8(pt + 8);
    }
    __syncthreads();
    const int lane = t & 63, wave = t >> 6;
    const int lr = lane & 15, kg = lane >> 4;
    const int n0 = wave * 64;

    // phase A: S0
    {
        f32x4 acc[4] = {};
        for (int k0 = 0; k0 < 256; k0 += 32) {
            int k = k0 + kg * 8;
            short8 a = *(const short8*)&Ax[lr][k];
#pragma unroll
            for (int nf = 0; nf < 4; ++nf) {
                short8 b = *(const short8*)(Wbf + (size_t)(n0 + nf * 16 + lr) * 256 + k);
                acc[nf] = __builtin_amdgcn_mfma_f32_16x16x32_bf16(a, b, acc[nf], 0, 0, 0);
            }
        }
#pragma unroll
        for (int nf = 0; nf < 4; ++nf) {
            int n = n0 + nf * 16 + lr;
            float bn = embed_b[n];
#pragma unroll
            for (int r = 0; r < 4; ++r) {
                u16 bv = f2bf(acc[nf][r] + bn);
                S_hist[(size_t)(row0 + kg * 4 + r) * 256 + n] = bv;
                S0[kg * 4 + r][n] = bv;
            }
        }
    }
    __syncthreads();

    // phase B: sn = S0 @ Wsn0^T, tn = Tn @ Wtn0^T
    {
        const u16* Wsn = Wbf + (size_t)5 * 65536;
        const u16* Wtn = Wbf + (size_t)1 * 65536;
        f32x4 aS[4] = {}, aT[4] = {};
        for (int k0 = 0; k0 < 256; k0 += 32) {
            int k = k0 + kg * 8;
            short8 a1 = *(const short8*)&S0[lr][k];
            short8 a2 = *(const short8*)&Tn[lr][k];
#pragma unroll
            for (int nf = 0; nf < 4; ++nf) {
                size_t wo = (size_t)(n0 + nf * 16 + lr) * 256 + k;
                aS[nf] = __builtin_amdgcn_mfma_f32_16x16x32_bf16(a1, *(const short8*)(Wsn + wo), aS[nf], 0, 0, 0);
                aT[nf] = __builtin_amdgcn_mfma_f32_16x16x32_bf16(a2, *(const short8*)(Wtn + wo), aT[nf], 0, 0, 0);
            }
        }
#pragma unroll
        for (int nf = 0; nf < 4; ++nf) {
            int n = n0 + nf * 16 + lr;
            float bS = bsn[n], bT = btn[n];
#pragma unroll
            for (int r = 0; r < 4; ++r) {
                sn_g[(size_t)(row0 + kg * 4 + r) * 256 + n] = f2bf(aS[nf][r] + bS);
                tn_g[(size_t)(row0 + kg * 4 + r) * 256 + n] = f2bf(aT[nf][r] + bT);
            }
        }
    }
}

// ---------------- triple_next<I,LAST>: triple GEMM+gate -> S_{I+1}; then dual (or out) ----------------
// grid 512, 256 thr (4 waves), 16 rows; wave w -> cols 64w..64w+63.
template<int I, bool LAST>
__global__ __launch_bounds__(256, 4) void triple_next(
    const u16* __restrict__ tf_g, const u16* __restrict__ sf_g,
    const float* __restrict__ t_att, const u16* __restrict__ Wbf,
    const float* __restrict__ bt, const float* __restrict__ bs,
    const float* __restrict__ btn, const float* __restrict__ bsn,
    const float* __restrict__ out_b,
    u16* __restrict__ S_hist, u16* __restrict__ sn_g, u16* __restrict__ tn_g,
    float* __restrict__ outp)
{
    __shared__ __align__(16) u16 Tf[16][LPAD];
    __shared__ __align__(16) u16 Sf[16][LPAD];
    __shared__ __align__(16) u16 Sn[16][LPAD];
    __shared__ __align__(16) u16 Tx[16][LPAD];  // t_att[I+1,7] (unused if LAST)
    const int t = threadIdx.x;
    const int row0 = blockIdx.x * 16;
    {
        int r = t >> 4, c0 = (t & 15) * 16;
        size_t off = (size_t)(row0 + r) * 256 + c0;
        *(short8*)&Tf[r][c0]     = *(const short8*)(tf_g + off);
        *(short8*)&Tf[r][c0 + 8] = *(const short8*)(tf_g + off + 8);
        *(short8*)&Sf[r][c0]     = *(const short8*)(sf_g + off);
        *(short8*)&Sf[r][c0 + 8] = *(const short8*)(sf_g + off + 8);
        if constexpr (!LAST) {
            const float* pt = t_att + ((size_t)(I + 1) * 8 + 7) * BH + off;
            *(short8*)&Tx[r][c0]     = cvt8(pt);
            *(short8*)&Tx[r][c0 + 8] = cvt8(pt + 8);
        }
    }
    __syncthreads();
    const int lane = t & 63, wave = t >> 6;
    const int lr = lane & 15, kg = lane >> 4;
    const int n0 = wave * 64;

    // phase A: triple GEMM + gated combine -> Sn (LDS) [+ S_hist[I+1] global if !LAST]
    {
        const u16* Wt3 = Wbf + (size_t)(9 + I) * 65536;
        const u16* Ws1 = Wbf + (size_t)(13 + I) * 65536;
        const u16* Ws3 = Wbf + (size_t)(17 + I) * 65536;
        f32x4 aT[4] = {}, aG[4] = {}, aS[4] = {};
        for (int k0 = 0; k0 < 256; k0 += 32) {
            int k = k0 + kg * 8;
            short8 at = *(const short8*)&Tf[lr][k];
            short8 as = *(const short8*)&Sf[lr][k];
#pragma unroll
            for (int nf = 0; nf < 4; ++nf) {
                size_t wo = (size_t)(n0 + nf * 16 + lr) * 256 + k;
                aT[nf] = __builtin_amdgcn_mfma_f32_16x16x32_bf16(at, *(const short8*)(Wt3 + wo), aT[nf], 0, 0, 0);
                aG[nf] = __builtin_amdgcn_mfma_f32_16x16x32_bf16(as, *(const short8*)(Ws1 + wo), aG[nf], 0, 0, 0);
                aS[nf] = __builtin_amdgcn_mfma_f32_16x16x32_bf16(as, *(const short8*)(Ws3 + wo), aS[nf], 0, 0, 0);
            }
        }
        const float* b1 = bt + I * 768 + 512;
        const float* b2 = bs + I * 768;
        const float* b3 = bs + I * 768 + 512;
#pragma unroll
        for (int nf = 0; nf < 4; ++nf) {
            int n = n0 + nf * 16 + lr;
            float bb1 = b1[n], bb2 = b2[n], bb3 = b3[n];
#pragma unroll
            for (int r = 0; r < 4; ++r) {
                float gv = sigmoidf_(aG[nf][r] + bb2);
                float v = gv * (aS[nf][r] + bb3) + (1.f - gv) * (aT[nf][r] + bb1);
                u16 bv = f2bf(v);
                Sn[kg * 4 + r][n] = bv;
                if constexpr (!LAST)
                    S_hist[(size_t)(I + 1) * BH + (size_t)(row0 + kg * 4 + r) * 256 + n] = bv;
            }
        }
    }
    __syncthreads();

    if constexpr (!LAST) {
        // phase B: sn = Sn @ Wsn[I+1]^T, tn = Tx @ Wtn[I+1]^T
        const u16* Wsn = Wbf + (size_t)(5 + I + 1) * 65536;
        const u16* Wtn = Wbf + (size_t)(1 + I + 1) * 65536;
        f32x4 aS[4] = {}, aT[4] = {};
        for (int k0 = 0; k0 < 256; k0 += 32) {
            int k = k0 + kg * 8;
            short8 a1 = *(const short8*)&Sn[lr][k];
            short8 a2 = *(const short8*)&Tx[lr][k];
#pragma unroll
            for (int nf = 0; nf < 4; ++nf) {
                size_t wo = (size_t)(n0 + nf * 16 + lr) * 256 + k;
                aS[nf] = __builtin_amdgcn_mfma_f32_16x16x32_bf16(a1, *(const short8*)(Wsn + wo), aS[nf], 0, 0, 0);
                aT[nf] = __builtin_amdgcn_mfma_f32_16x16x32_bf16(a2, *(const short8*)(Wtn + wo), aT[nf], 0, 0, 0);
            }
        }
#pragma unroll
        for (int nf = 0; nf < 4; ++nf) {
            int n = n0 + nf * 16 + lr;
            float bS = bsn[(I + 1) * 256 + n], bT = btn[(I + 1) * 256 + n];
#pragma unroll
            for (int r = 0; r < 4; ++r) {
                sn_g[(size_t)(row0 + kg * 4 + r) * 256 + n] = f2bf(aS[nf][r] + bS);
                tn_g[(size_t)(row0 + kg * 4 + r) * 256 + n] = f2bf(aT[nf][r] + bT);
            }
        }
    } else {
        // phase B: out = tanh(Sn @ out_w^T + out_b), f32 (no S4 global round-trip)
        const u16* Wo = Wbf + (size_t)21 * 65536;
        f32x4 acc[4] = {};
        for (int k0 = 0; k0 < 256; k0 += 32) {
            int k = k0 + kg * 8;
            short8 a = *(const short8*)&Sn[lr][k];
#pragma unroll
            for (int nf = 0; nf < 4; ++nf) {
                short8 b = *(const short8*)(Wo + (size_t)(n0 + nf * 16 + lr) * 256 + k);
                acc[nf] = __builtin_amdgcn_mfma_f32_16x16x32_bf16(a, b, acc[nf], 0, 0, 0);
            }
        }
#pragma unroll
        for (int nf = 0; nf < 4; ++nf) {
            int n = n0 + nf * 16 + lr;
            float bn = out_b[n];
#pragma unroll
            for (int r = 0; r < 4; ++r)
                outp[(size_t)(row0 + kg * 4 + r) * 256 + n] = tanhf(acc[nf][r] + bn);
        }
    }
}

// ---------------- attention: one wave per row, plain loads, default occupancy ----------------
// grid 2048 x 256 thr (4 rows/block). R15-proven.
template<int I>
__global__ __launch_bounds__(256) void attn_k(
    const float* __restrict__ t_att, const float* __restrict__ s_att,
    const u16* __restrict__ S_hist,
    const u16* __restrict__ sn_g, const u16* __restrict__ tn_g,
    u16* __restrict__ tf_g, u16* __restrict__ sf_g)
{
    const int lane = threadIdx.x & 63;
    const int row = blockIdx.x * 4 + (threadIdx.x >> 6);
    const size_t ro = (size_t)row * 256 + lane * 4;
    const float scale = 0.0625f;  // 1/sqrt(256)

    const float* sa = s_att + (size_t)I * 8 * BH + ro;
    const float* ta = t_att + (size_t)I * 8 * BH + ro;

    us4 snu = *(const us4*)(sn_g + ro);
    us4 tnu = *(const us4*)(tn_g + ro);
    us4 scu = *(const us4*)(S_hist + (size_t)I * BH + ro);
    us4 shu[I > 0 ? I : 1];
#pragma unroll
    for (int jj = 0; jj < I; ++jj) shu[jj] = *(const us4*)(S_hist + (size_t)jj * BH + ro);

    f32x4 sav[7], tav[8], tsp[I > 0 ? I : 1];
#pragma unroll
    for (int kk = 0; kk < 7; ++kk) sav[kk] = *(const f32x4*)(sa + (size_t)(kk + 1) * BH);
#pragma unroll
    for (int kk = 0; kk < 8; ++kk) tav[kk] = *(const f32x4*)(ta + (size_t)kk * BH);
#pragma unroll
    for (int jj = 0; jj < I; ++jj) tsp[jj] = *(const f32x4*)(t_att + ((size_t)jj * 8 + 7) * BH + ro);

    float sn[4], tn[4], Sc[4];
#pragma unroll
    for (int j = 0; j < 4; ++j) { sn[j] = bf2f(snu[j]); tn[j] = bf2f(tnu[j]); Sc[j] = bf2f(scu[j]); }

    constexpr int NV = 9 + I;
    float v[NV];
#pragma unroll
    for (int kk = 0; kk < 7; ++kk) v[kk] = dot4(sav[kk], sn);
    v[7] = Sc[0] * sn[0] + Sc[1] * sn[1] + Sc[2] * sn[2] + Sc[3] * sn[3];
#pragma unroll
    for (int jj = 0; jj < I; ++jj) v[8 + jj] = dot4(tsp[jj], tn);
    v[8 + I] = dot4(tav[7], tn);

    // single 6-level butterfly over all NV values
#pragma unroll
    for (int o = 32; o > 0; o >>= 1)
#pragma unroll
        for (int u = 0; u < NV; ++u) v[u] += __shfl_xor(v[u], o);

    // temporal softmax + T_fusion
    float m = v[0] * scale;
#pragma unroll
    for (int kk = 1; kk < 8; ++kk) m = fmaxf(m, v[kk] * scale);
    float w8[8], den = 0.f;
#pragma unroll
    for (int kk = 0; kk < 8; ++kk) { w8[kk] = __expf(v[kk] * scale - m); den += w8[kk]; }
    float inv = 1.f / den;

    float Tt[4] = {0.f, 0.f, 0.f, 0.f};
#pragma unroll
    for (int kk = 0; kk < 8; ++kk)
#pragma unroll
        for (int j = 0; j < 4; ++j) Tt[j] += w8[kk] * tav[kk][j];
    us4 ot;
#pragma unroll
    for (int j = 0; j < 4; ++j) {
        float g = sigmoidf_(tn[j]);
        ot[j] = f2bf(tav[7][j] * g + (1.f - g) * Tt[j] * inv);
    }
    *(us4*)(tf_g + ro) = ot;

    // spatial softmax: keys = [zeros x (7-I), t_att[0,7]..t_att[I,7]]
    float ms = fmaxf(0.f, v[8 + I] * scale);
#pragma unroll
    for (int jj = 0; jj < I; ++jj) ms = fmaxf(ms, v[8 + jj] * scale);
    float dens = (float)(7 - I) * __expf(-ms);
    float St[4];
    {
        float w = __expf(v[8 + I] * scale - ms);
        dens += w;
#pragma unroll
        for (int j = 0; j < 4; ++j) St[j] = w * Sc[j];
    }
#pragma unroll
    for (int jj = 0; jj < I; ++jj) {
        float w = __expf(v[8 + jj] * scale - ms);
        dens += w;
#pragma unroll
        for (int j = 0; j < 4; ++j) St[j] += w * bf2f(shu[jj][j]);
    }
    float invs = 1.f / dens;
    us4 os;
#pragma unroll
    for (int j = 0; j < 4; ++j) {
        float g = sigmoidf_(sn[j]);
        os[j] = f2bf(Sc[j] * g + (1.f - g) * St[j] * invs);
    }
    *(us4*)(sf_g + ro) = os;
}

extern "C" void kernel_launch(void* const* d_in, const int* in_sizes, int n_in,
                              void* d_out, int out_size, void* d_ws, size_t ws_size,
                              hipStream_t stream)
{
    (void)in_sizes; (void)n_in; (void)out_size; (void)ws_size;
    const float* x       = (const float*)d_in[0];
    const float* t_att   = (const float*)d_in[1];
    const float* s_att   = (const float*)d_in[2];
    const float* embed_w = (const float*)d_in[3];
    const float* embed_b = (const float*)d_in[4];
    const float* wtn     = (const float*)d_in[5];
    const float* btn     = (const float*)d_in[6];
    const float* wsn     = (const float*)d_in[7];
    const float* bsn     = (const float*)d_in[8];
    const float* wt      = (const float*)d_in[9];
    const float* bt      = (const float*)d_in[10];
    const float* ws_in   = (const float*)d_in[11];
    const float* bs      = (const float*)d_in[12];
    const float* out_w   = (const float*)d_in[13];
    const float* out_b   = (const float*)d_in[14];

    u16* wsp    = (u16*)d_ws;
    u16* Wbf    = wsp;                       // 22 * 65536 u16
    u16* S_hist = wsp + (size_t)22 * 65536;  // 4 * BH (S0..S3; S4 never materialized)
    u16* sn_g   = S_hist + 4 * BH;
    u16* tn_g   = sn_g + BH;
    u16* tf_g   = tn_g + BH;
    u16* sf_g   = tf_g + BH;

    convert_weights<<<1408, 256, 0, stream>>>(embed_w, wtn, wsn, wt, ws_in, out_w, Wbf);

    embed_dual<<<BATCH / 16, 256, 0, stream>>>(x, t_att, Wbf, embed_b, btn, bsn,
                                               S_hist, sn_g, tn_g);

    attn_k<0><<<BATCH / 4, 256, 0, stream>>>(t_att, s_att, S_hist, sn_g, tn_g, tf_g, sf_g);
    triple_next<0, false><<<BATCH / 16, 256, 0, stream>>>(
        tf_g, sf_g, t_att, Wbf, bt, bs, btn, bsn, out_b, S_hist, sn_g, tn_g, nullptr);

    attn_k<1><<<BATCH / 4, 256, 0, stream>>>(t_att, s_att, S_hist, sn_g, tn_g, tf_g, sf_g);
    triple_next<1, false><<<BATCH / 16, 256, 0, stream>>>(
        tf_g, sf_g, t_att, Wbf, bt, bs, btn, bsn, out_b, S_hist, sn_g, tn_g, nullptr);

    attn_k<2><<<BATCH / 4, 256, 0, stream>>>(t_att, s_att, S_hist, sn_g, tn_g, tf_g, sf_g);
    triple_next<2, false><<<BATCH / 16, 256, 0, stream>>>(
        tf_g, sf_g, t_att, Wbf, bt, bs, btn, bsn, out_b, S_hist, sn_g, tn_g, nullptr);

    attn_k<3><<<BATCH / 4, 256, 0, stream>>>(t_att, s_att, S_hist, sn_g, tn_g, tf_g, sf_g);
    triple_next<3, true><<<BATCH / 16, 256, 0, stream>>>(
        tf_g, sf_g, t_att, Wbf, bt, bs, btn, bsn, out_b, S_hist, sn_g, tn_g, (float*)d_out);
}

// Round 17
// 264.315 us; speedup vs baseline: 1.2730x; 1.2730x over previous
//
#include <hip/hip_runtime.h>
#include <cmath>

typedef __attribute__((ext_vector_type(8))) short short8;
typedef __attribute__((ext_vector_type(4))) float f32x4;
typedef __attribute__((ext_vector_type(4))) unsigned short us4;
typedef unsigned short u16;

#define BATCH 8192
static constexpr size_t BH = (size_t)BATCH * 256;
#define LPAD 264  // u16 LDS row stride (528 B)

__device__ __forceinline__ u16 f2bf(float f) {
    union { float f; unsigned u; } v; v.f = f;
    unsigned r = v.u + 0x7FFFu + ((v.u >> 16) & 1u);
    return (u16)(r >> 16);
}
__device__ __forceinline__ float bf2f(u16 u) {
    union { unsigned u; float f; } v; v.u = ((unsigned)u) << 16;
    return v.f;
}
__device__ __forceinline__ float sigmoidf_(float x) {
    return 1.f / (1.f + __expf(-x));
}
__device__ __forceinline__ short8 cvt8(const float* p) {
    f32x4 lo = *(const f32x4*)p, hi = *(const f32x4*)(p + 4);
    short8 t;
    t[0] = (short)f2bf(lo[0]); t[1] = (short)f2bf(lo[1]);
    t[2] = (short)f2bf(lo[2]); t[3] = (short)f2bf(lo[3]);
    t[4] = (short)f2bf(hi[0]); t[5] = (short)f2bf(hi[1]);
    t[6] = (short)f2bf(hi[2]); t[7] = (short)f2bf(hi[3]);
    return t;
}
__device__ __forceinline__ float dot4(const f32x4& a, const float* b) {
    return a[0] * b[0] + a[1] * b[1] + a[2] * b[2] + a[3] * b[3];
}

// ---------------- weight conversion ----------------
// dst layout (u16 units, 65536 per chunk):
//  c0: embed_w | c1..4: wtn[l] | c5..8: wsn[l] | c9..12: wt[l][512:768]
//  c13..16: ws[l][0:256] | c17..20: ws[l][512:768] | c21: out_w
__global__ __launch_bounds__(256) void convert_weights(
    const float* __restrict__ embed_w, const float* __restrict__ wtn,
    const float* __restrict__ wsn, const float* __restrict__ wt,
    const float* __restrict__ ws, const float* __restrict__ out_w,
    u16* __restrict__ dst)
{
    int idx = blockIdx.x * 256 + threadIdx.x;
    int e = idx * 4;
    if (e >= 22 * 65536) return;
    int c = e >> 16, o = e & 65535;
    const float* src;
    if (c == 0)      src = embed_w + o;
    else if (c < 5)  src = wtn + (size_t)(c - 1) * 65536 + o;
    else if (c < 9)  src = wsn + (size_t)(c - 5) * 65536 + o;
    else if (c < 13) src = wt + (size_t)(c - 9) * 768 * 256 + 512 * 256 + o;
    else if (c < 17) src = ws + (size_t)(c - 13) * 768 * 256 + o;
    else if (c < 21) src = ws + (size_t)(c - 17) * 768 * 256 + 512 * 256 + o;
    else             src = out_w + o;
    f32x4 v = *(const f32x4*)src;
    us4 r;
#pragma unroll
    for (int j = 0; j < 4; ++j) r[j] = f2bf(v[j]);
    *(us4*)(dst + e) = r;
}

// ---------------- gemm_one: C[8192,256] = A @ W^T + b ----------------
// block 256 thr (4 waves): M=32 (row0=bx*32), N=128 (col0=by*128); wave w -> 32 cols.
// A staged once in LDS; W streamed from L2 (weights amortized over 32 rows).
template<bool A_F32, int ACT>
__global__ __launch_bounds__(256, 4) void gemm_one(
    const void* __restrict__ Ap, const u16* __restrict__ W,
    const float* __restrict__ bias, void* __restrict__ Cp)
{
    __shared__ __align__(16) u16 A[32][LPAD];
    const int t = threadIdx.x;
    const int row0 = blockIdx.x * 32;
    {
        int r = t >> 3, c0 = (t & 7) * 32;
        if constexpr (A_F32) {
            const float* p = (const float*)Ap + (size_t)(row0 + r) * 256 + c0;
#pragma unroll
            for (int j = 0; j < 4; ++j) *(short8*)&A[r][c0 + j * 8] = cvt8(p + j * 8);
        } else {
            const u16* p = (const u16*)Ap + (size_t)(row0 + r) * 256 + c0;
#pragma unroll
            for (int j = 0; j < 4; ++j) *(short8*)&A[r][c0 + j * 8] = *(const short8*)(p + j * 8);
        }
    }
    __syncthreads();
    const int lane = t & 63, wave = t >> 6;
    const int lr = lane & 15, kg = lane >> 4;
    const int col0 = blockIdx.y * 128 + wave * 32;
    f32x4 acc[2][2] = {};
    for (int k0 = 0; k0 < 256; k0 += 32) {
        int k = k0 + kg * 8;
        short8 a0 = *(const short8*)&A[lr][k];
        short8 a1 = *(const short8*)&A[16 + lr][k];
#pragma unroll
        for (int nt = 0; nt < 2; ++nt) {
            short8 b = *(const short8*)(W + (size_t)(col0 + nt * 16 + lr) * 256 + k);
            acc[0][nt] = __builtin_amdgcn_mfma_f32_16x16x32_bf16(a0, b, acc[0][nt], 0, 0, 0);
            acc[1][nt] = __builtin_amdgcn_mfma_f32_16x16x32_bf16(a1, b, acc[1][nt], 0, 0, 0);
        }
    }
#pragma unroll
    for (int nt = 0; nt < 2; ++nt) {
        int n = col0 + nt * 16 + lr;
        float bn = bias[n];
#pragma unroll
        for (int mt = 0; mt < 2; ++mt) {
            int m0 = row0 + mt * 16 + kg * 4;
#pragma unroll
            for (int r = 0; r < 4; ++r) {
                float v = acc[mt][nt][r] + bn;
                if constexpr (ACT == 0) ((u16*)Cp)[(size_t)(m0 + r) * 256 + n] = f2bf(v);
                else                    ((float*)Cp)[(size_t)(m0 + r) * 256 + n] = tanhf(v);
            }
        }
    }
}

// ---------------- gemm_dual: z=0 -> s_next (bf16 A), z=1 -> t_next (f32 A) ----------------
__global__ __launch_bounds__(256, 4) void gemm_dual(
    const u16* __restrict__ Scur, const float* __restrict__ Tlast,
    const u16* __restrict__ Wsn, const u16* __restrict__ Wtn,
    const float* __restrict__ bsn_l, const float* __restrict__ btn_l,
    u16* __restrict__ sn_g, u16* __restrict__ tn_g)
{
    __shared__ __align__(16) u16 A[32][LPAD];
    const int t = threadIdx.x;
    const int row0 = blockIdx.x * 32;
    const int g = blockIdx.z;
    {
        int r = t >> 3, c0 = (t & 7) * 32;
        if (g) {
            const float* p = Tlast + (size_t)(row0 + r) * 256 + c0;
#pragma unroll
            for (int j = 0; j < 4; ++j) *(short8*)&A[r][c0 + j * 8] = cvt8(p + j * 8);
        } else {
            const u16* p = Scur + (size_t)(row0 + r) * 256 + c0;
#pragma unroll
            for (int j = 0; j < 4; ++j) *(short8*)&A[r][c0 + j * 8] = *(const short8*)(p + j * 8);
        }
    }
    __syncthreads();
    const int lane = t & 63, wave = t >> 6;
    const int lr = lane & 15, kg = lane >> 4;
    const int col0 = blockIdx.y * 128 + wave * 32;
    const u16* W = g ? Wtn : Wsn;
    f32x4 acc[2][2] = {};
    for (int k0 = 0; k0 < 256; k0 += 32) {
        int k = k0 + kg * 8;
        short8 a0 = *(const short8*)&A[lr][k];
        short8 a1 = *(const short8*)&A[16 + lr][k];
#pragma unroll
        for (int nt = 0; nt < 2; ++nt) {
            short8 b = *(const short8*)(W + (size_t)(col0 + nt * 16 + lr) * 256 + k);
            acc[0][nt] = __builtin_amdgcn_mfma_f32_16x16x32_bf16(a0, b, acc[0][nt], 0, 0, 0);
            acc[1][nt] = __builtin_amdgcn_mfma_f32_16x16x32_bf16(a1, b, acc[1][nt], 0, 0, 0);
        }
    }
    const float* bias = g ? btn_l : bsn_l;
    u16* dst = g ? tn_g : sn_g;
#pragma unroll
    for (int nt = 0; nt < 2; ++nt) {
        int n = col0 + nt * 16 + lr;
        float bn = bias[n];
#pragma unroll
        for (int mt = 0; mt < 2; ++mt) {
            int m0 = row0 + mt * 16 + kg * 4;
#pragma unroll
            for (int r = 0; r < 4; ++r)
                dst[(size_t)(m0 + r) * 256 + n] = f2bf(acc[mt][nt][r] + bn);
        }
    }
}

// ---------------- gemm_triple: 3 GEMMs + gated combine -> S_{i+1} ----------------
__global__ __launch_bounds__(256, 2) void gemm_triple(
    const u16* __restrict__ Tf, const u16* __restrict__ Sf,
    const u16* __restrict__ Wt3, const u16* __restrict__ Ws1, const u16* __restrict__ Ws3,
    const float* __restrict__ b1p, const float* __restrict__ b2p, const float* __restrict__ b3p,
    u16* __restrict__ Sout)
{
    __shared__ __align__(16) u16 At[32][LPAD];
    __shared__ __align__(16) u16 As[32][LPAD];
    const int t = threadIdx.x;
    const int row0 = blockIdx.x * 32;
    {
        int r = t >> 3, c0 = (t & 7) * 32;
        size_t off = (size_t)(row0 + r) * 256 + c0;
#pragma unroll
        for (int j = 0; j < 4; ++j) {
            *(short8*)&At[r][c0 + j * 8] = *(const short8*)(Tf + off + j * 8);
            *(short8*)&As[r][c0 + j * 8] = *(const short8*)(Sf + off + j * 8);
        }
    }
    __syncthreads();
    const int lane = t & 63, wave = t >> 6;
    const int lr = lane & 15, kg = lane >> 4;
    const int col0 = blockIdx.y * 128 + wave * 32;
    f32x4 aT[2][2] = {}, aG[2][2] = {}, aS[2][2] = {};
    for (int k0 = 0; k0 < 256; k0 += 32) {
        int k = k0 + kg * 8;
        short8 at0 = *(const short8*)&At[lr][k];
        short8 at1 = *(const short8*)&At[16 + lr][k];
        short8 as0 = *(const short8*)&As[lr][k];
        short8 as1 = *(const short8*)&As[16 + lr][k];
#pragma unroll
        for (int nt = 0; nt < 2; ++nt) {
            size_t wo = (size_t)(col0 + nt * 16 + lr) * 256 + k;
            short8 bT = *(const short8*)(Wt3 + wo);
            short8 bG = *(const short8*)(Ws1 + wo);
            short8 bS = *(const short8*)(Ws3 + wo);
            aT[0][nt] = __builtin_amdgcn_mfma_f32_16x16x32_bf16(at0, bT, aT[0][nt], 0, 0, 0);
            aT[1][nt] = __builtin_amdgcn_mfma_f32_16x16x32_bf16(at1, bT, aT[1][nt], 0, 0, 0);
            aG[0][nt] = __builtin_amdgcn_mfma_f32_16x16x32_bf16(as0, bG, aG[0][nt], 0, 0, 0);
            aG[1][nt] = __builtin_amdgcn_mfma_f32_16x16x32_bf16(as1, bG, aG[1][nt], 0, 0, 0);
            aS[0][nt] = __builtin_amdgcn_mfma_f32_16x16x32_bf16(as0, bS, aS[0][nt], 0, 0, 0);
            aS[1][nt] = __builtin_amdgcn_mfma_f32_16x16x32_bf16(as1, bS, aS[1][nt], 0, 0, 0);
        }
    }
#pragma unroll
    for (int nt = 0; nt < 2; ++nt) {
        int n = col0 + nt * 16 + lr;
        float bb1 = b1p[n], bb2 = b2p[n], bb3 = b3p[n];
#pragma unroll
        for (int mt = 0; mt < 2; ++mt) {
            int m0 = row0 + mt * 16 + kg * 4;
#pragma unroll
            for (int r = 0; r < 4; ++r) {
                float gv = sigmoidf_(aG[mt][nt][r] + bb2);
                float v = gv * (aS[mt][nt][r] + bb3) + (1.f - gv) * (aT[mt][nt][r] + bb1);
                Sout[(size_t)(m0 + r) * 256 + n] = f2bf(v);
            }
        }
    }
}

// ---------------- attention: one wave per row, plain loads, default occupancy ----------------
// grid 2048 x 256 thr (4 rows/block). R1/R15-proven TLP regime +
// single merged butterfly (one 6-level chain for all 9+I logits).
template<int I>
__global__ __launch_bounds__(256) void attn_k(
    const float* __restrict__ t_att, const float* __restrict__ s_att,
    const u16* __restrict__ S_hist,
    const u16* __restrict__ sn_g, const u16* __restrict__ tn_g,
    u16* __restrict__ tf_g, u16* __restrict__ sf_g)
{
    const int lane = threadIdx.x & 63;
    const int row = blockIdx.x * 4 + (threadIdx.x >> 6);
    const size_t ro = (size_t)row * 256 + lane * 4;
    const float scale = 0.0625f;  // 1/sqrt(256)

    const float* sa = s_att + (size_t)I * 8 * BH + ro;
    const float* ta = t_att + (size_t)I * 8 * BH + ro;

    us4 snu = *(const us4*)(sn_g + ro);
    us4 tnu = *(const us4*)(tn_g + ro);
    us4 scu = *(const us4*)(S_hist + (size_t)I * BH + ro);
    us4 shu[I > 0 ? I : 1];
#pragma unroll
    for (int jj = 0; jj < I; ++jj) shu[jj] = *(const us4*)(S_hist + (size_t)jj * BH + ro);

    f32x4 sav[7], tav[8], tsp[I > 0 ? I : 1];
#pragma unroll
    for (int kk = 0; kk < 7; ++kk) sav[kk] = *(const f32x4*)(sa + (size_t)(kk + 1) * BH);
#pragma unroll
    for (int kk = 0; kk < 8; ++kk) tav[kk] = *(const f32x4*)(ta + (size_t)kk * BH);
#pragma unroll
    for (int jj = 0; jj < I; ++jj) tsp[jj] = *(const f32x4*)(t_att + ((size_t)jj * 8 + 7) * BH + ro);

    float sn[4], tn[4], Sc[4];
#pragma unroll
    for (int j = 0; j < 4; ++j) { sn[j] = bf2f(snu[j]); tn[j] = bf2f(tnu[j]); Sc[j] = bf2f(scu[j]); }

    constexpr int NV = 9 + I;
    float v[NV];
#pragma unroll
    for (int kk = 0; kk < 7; ++kk) v[kk] = dot4(sav[kk], sn);
    v[7] = Sc[0] * sn[0] + Sc[1] * sn[1] + Sc[2] * sn[2] + Sc[3] * sn[3];
#pragma unroll
    for (int jj = 0; jj < I; ++jj) v[8 + jj] = dot4(tsp[jj], tn);
    v[8 + I] = dot4(tav[7], tn);

    // single 6-level butterfly over all NV values
#pragma unroll
    for (int o = 32; o > 0; o >>= 1)
#pragma unroll
        for (int u = 0; u < NV; ++u) v[u] += __shfl_xor(v[u], o);

    // temporal softmax + T_fusion
    float m = v[0] * scale;
#pragma unroll
    for (int kk = 1; kk < 8; ++kk) m = fmaxf(m, v[kk] * scale);
    float w8[8], den = 0.f;
#pragma unroll
    for (int kk = 0; kk < 8; ++kk) { w8[kk] = __expf(v[kk] * scale - m); den += w8[kk]; }
    float inv = 1.f / den;

    float Tt[4] = {0.f, 0.f, 0.f, 0.f};
#pragma unroll
    for (int kk = 0; kk < 8; ++kk)
#pragma unroll
        for (int j = 0; j < 4; ++j) Tt[j] += w8[kk] * tav[kk][j];
    us4 ot;
#pragma unroll
    for (int j = 0; j < 4; ++j) {
        float g = sigmoidf_(tn[j]);
        ot[j] = f2bf(tav[7][j] * g + (1.f - g) * Tt[j] * inv);
    }
    *(us4*)(tf_g + ro) = ot;

    // spatial softmax: keys = [zeros x (7-I), t_att[0,7]..t_att[I,7]]
    float ms = fmaxf(0.f, v[8 + I] * scale);
#pragma unroll
    for (int jj = 0; jj < I; ++jj) ms = fmaxf(ms, v[8 + jj] * scale);
    float dens = (float)(7 - I) * __expf(-ms);
    float St[4];
    {
        float w = __expf(v[8 + I] * scale - ms);
        dens += w;
#pragma unroll
        for (int j = 0; j < 4; ++j) St[j] = w * Sc[j];
    }
#pragma unroll
    for (int jj = 0; jj < I; ++jj) {
        float w = __expf(v[8 + jj] * scale - ms);
        dens += w;
#pragma unroll
        for (int j = 0; j < 4; ++j) St[j] += w * bf2f(shu[jj][j]);
    }
    float invs = 1.f / dens;
    us4 os;
#pragma unroll
    for (int j = 0; j < 4; ++j) {
        float g = sigmoidf_(sn[j]);
        os[j] = f2bf(Sc[j] * g + (1.f - g) * St[j] * invs);
    }
    *(us4*)(sf_g + ro) = os;
}

extern "C" void kernel_launch(void* const* d_in, const int* in_sizes, int n_in,
                              void* d_out, int out_size, void* d_ws, size_t ws_size,
                              hipStream_t stream)
{
    (void)in_sizes; (void)n_in; (void)out_size; (void)ws_size;
    const float* x       = (const float*)d_in[0];
    const float* t_att   = (const float*)d_in[1];
    const float* s_att   = (const float*)d_in[2];
    const float* embed_w = (const float*)d_in[3];
    const float* embed_b = (const float*)d_in[4];
    const float* wtn     = (const float*)d_in[5];
    const float* btn     = (const float*)d_in[6];
    const float* wsn     = (const float*)d_in[7];
    const float* bsn     = (const float*)d_in[8];
    const float* wt      = (const float*)d_in[9];
    const float* bt      = (const float*)d_in[10];
    const float* ws_in   = (const float*)d_in[11];
    const float* bs      = (const float*)d_in[12];
    const float* out_w   = (const float*)d_in[13];
    const float* out_b   = (const float*)d_in[14];

    u16* wsp    = (u16*)d_ws;
    u16* Wbf    = wsp;                       // 22 * 65536 u16
    u16* S_hist = wsp + (size_t)22 * 65536;  // 5 * BH
    u16* sn_g   = S_hist + 5 * BH;
    u16* tn_g   = sn_g + BH;
    u16* tf_g   = tn_g + BH;
    u16* sf_g   = tf_g + BH;

    convert_weights<<<1408, 256, 0, stream>>>(embed_w, wtn, wsn, wt, ws_in, out_w, Wbf);

    dim3 g2(256, 2);

    // S0 = x @ embed_w^T + embed_b
    gemm_one<true, 0><<<g2, 256, 0, stream>>>(x, Wbf, embed_b, S_hist);

    for (int i = 0; i < 4; ++i) {
        gemm_dual<<<dim3(256, 2, 2), 256, 0, stream>>>(
            S_hist + (size_t)i * BH, t_att + ((size_t)i * 8 + 7) * BH,
            Wbf + (size_t)(5 + i) * 65536, Wbf + (size_t)(1 + i) * 65536,
            bsn + i * 256, btn + i * 256, sn_g, tn_g);

        switch (i) {
            case 0: attn_k<0><<<BATCH / 4, 256, 0, stream>>>(t_att, s_att, S_hist, sn_g, tn_g, tf_g, sf_g); break;
            case 1: attn_k<1><<<BATCH / 4, 256, 0, stream>>>(t_att, s_att, S_hist, sn_g, tn_g, tf_g, sf_g); break;
            case 2: attn_k<2><<<BATCH / 4, 256, 0, stream>>>(t_att, s_att, S_hist, sn_g, tn_g, tf_g, sf_g); break;
            case 3: attn_k<3><<<BATCH / 4, 256, 0, stream>>>(t_att, s_att, S_hist, sn_g, tn_g, tf_g, sf_g); break;
        }

        gemm_triple<<<g2, 256, 0, stream>>>(
            tf_g, sf_g,
            Wbf + (size_t)(9 + i) * 65536,
            Wbf + (size_t)(13 + i) * 65536,
            Wbf + (size_t)(17 + i) * 65536,
            bt + i * 768 + 512, bs + i * 768, bs + i * 768 + 512,
            S_hist + (size_t)(i + 1) * BH);
    }

    // out = tanh(S4 @ out_w^T + out_b), f32
    gemm_one<false, 1><<<g2, 256, 0, stream>>>(
        S_hist + (size_t)4 * BH, Wbf + (size_t)21 * 65536, out_b, (float*)d_out);
}